// Round 2
// baseline (568.811 us; speedup 1.0000x reference)
//
#include <hip/hip_runtime.h>

#define KK 32
#define BATCH 512
#define DD 2048

// ---------------------------------------------------------------------------
// Tree-max over a fully-unrolled register array (5-deep dependency chain
// instead of 31-deep sequential fmaxf).
// ---------------------------------------------------------------------------
__device__ __forceinline__ float regmax_tree(const float p[KK]) {
  float t[KK];
#pragma unroll
  for (int i = 0; i < KK; ++i) t[i] = p[i];
#pragma unroll
  for (int s = KK / 2; s >= 1; s >>= 1) {
#pragma unroll
    for (int i = 0; i < s; ++i) t[i] = fmaxf(t[i], t[i + s]);
  }
  return t[0];
}

// ---------------------------------------------------------------------------
// One log-matmul-exp node: out[j] = log( sum_i exp(prod[i]-m) * W[i][j] ) + m
// FULLY unrolled: e[] stays in registers (no LDS round trip), W is
// wave-uniform (same node for all 64 lanes) -> scalar s_load into SGPRs,
// straight-line 1024-FMA body gives the scheduler freedom to pipeline the
// s_loads behind the FMAs.
// ---------------------------------------------------------------------------
__device__ __forceinline__ void lse_node(const float prod[KK],
                                         const float* __restrict__ Wn,
                                         float out[KK]) {
  const float m = regmax_tree(prod);
  float e[KK];
#pragma unroll
  for (int i = 0; i < KK; ++i) e[i] = __expf(prod[i] - m);

  float acc[KK];
#pragma unroll
  for (int j = 0; j < KK; ++j) acc[j] = 0.0f;

#pragma unroll
  for (int i = 0; i < KK; ++i) {
#pragma unroll
    for (int j = 0; j < KK; ++j) acc[j] = fmaf(e[i], Wn[i * KK + j], acc[j]);
  }

#pragma unroll
  for (int j = 0; j < KK; ++j) out[j] = __logf(acc[j]) + m;
}

__device__ __forceinline__ void addv(const float a[KK], const float b[KK],
                                     float o[KK]) {
#pragma unroll
  for (int j = 0; j < KK; ++j) o[j] = a[j] + b[j];
}

// Leaf pair from x (layout [B][D][K], contiguous K): 64 consecutive floats.
__device__ __forceinline__ void leafpair_x(const float* __restrict__ xb,
                                           int leaf, float prod[KK]) {
  const float4* p = reinterpret_cast<const float4*>(xb + (size_t)leaf * KK);
#pragma unroll
  for (int q = 0; q < KK / 4; ++q) {
    const float4 u = p[q];
    const float4 v = p[q + KK / 4];
    prod[4 * q + 0] = u.x + v.x;
    prod[4 * q + 1] = u.y + v.y;
    prod[4 * q + 2] = u.z + v.z;
    prod[4 * q + 3] = u.w + v.w;
  }
}

// Leaf pair from intermediate buffer (layout [node][K][BATCH]) -> coalesced.
__device__ __forceinline__ void leafpair_n(const float* __restrict__ in,
                                           int leaf, int b, float prod[KK]) {
  const float* p0 = in + (size_t)leaf * (KK * BATCH) + b;
  const float* p1 = p0 + (KK * BATCH);
#pragma unroll
  for (int j = 0; j < KK; ++j) prod[j] = p0[j * BATCH] + p1[j * BATCH];
}

// ---------------------------------------------------------------------------
// Kernel A: levels 1-3.  Each thread reduces an 8-leaf subtree (7 nodes).
// grid (256 chunks, 8 batch-groups), block 64 (lane = batch).
// ---------------------------------------------------------------------------
__global__ __launch_bounds__(64, 2) void kernA(const float* __restrict__ x,
                                               const float* __restrict__ W,
                                               float* __restrict__ o1) {
  const int lane = threadIdx.x;
  const int b = blockIdx.y * 64 + lane;
  const int chunk = blockIdx.x;  // 0..255
  const float* xb = x + (size_t)b * (DD * KK);
  const int leaf0 = chunk * 8;

  float r0[KK], r1[KK], r2[KK], prod[KK];

  leafpair_x(xb, leaf0 + 0, prod);
  lse_node(prod, W + (size_t)(chunk * 4 + 0) * (KK * KK), r0);
  leafpair_x(xb, leaf0 + 2, prod);
  lse_node(prod, W + (size_t)(chunk * 4 + 1) * (KK * KK), r1);
  addv(r0, r1, prod);
  lse_node(prod, W + (size_t)(1024 + chunk * 2 + 0) * (KK * KK), r0);
  leafpair_x(xb, leaf0 + 4, prod);
  lse_node(prod, W + (size_t)(chunk * 4 + 2) * (KK * KK), r1);
  leafpair_x(xb, leaf0 + 6, prod);
  lse_node(prod, W + (size_t)(chunk * 4 + 3) * (KK * KK), r2);
  addv(r1, r2, prod);
  lse_node(prod, W + (size_t)(1024 + chunk * 2 + 1) * (KK * KK), r1);
  addv(r0, r1, prod);
  lse_node(prod, W + (size_t)(1536 + chunk) * (KK * KK), r0);

#pragma unroll
  for (int j = 0; j < KK; ++j)
    o1[(size_t)chunk * (KK * BATCH) + j * BATCH + b] = r0[j];
}

// ---------------------------------------------------------------------------
// Mid kernel: 3 levels, 8 input nodes -> 1 output node per thread.
// Used for 256->32 (offs 1792/1920/1984) and 32->4 (offs 2016/2032/2040).
// ---------------------------------------------------------------------------
__global__ __launch_bounds__(64, 2) void kernMid(const float* __restrict__ in,
                                                 const float* __restrict__ W,
                                                 float* __restrict__ o,
                                                 int offA, int offB2, int offC) {
  const int lane = threadIdx.x;
  const int b = blockIdx.y * 64 + lane;
  const int chunk = blockIdx.x;
  const int leaf0 = chunk * 8;

  float r0[KK], r1[KK], r2[KK], prod[KK];

  leafpair_n(in, leaf0 + 0, b, prod);
  lse_node(prod, W + (size_t)(offA + chunk * 4 + 0) * (KK * KK), r0);
  leafpair_n(in, leaf0 + 2, b, prod);
  lse_node(prod, W + (size_t)(offA + chunk * 4 + 1) * (KK * KK), r1);
  addv(r0, r1, prod);
  lse_node(prod, W + (size_t)(offB2 + chunk * 2 + 0) * (KK * KK), r0);
  leafpair_n(in, leaf0 + 4, b, prod);
  lse_node(prod, W + (size_t)(offA + chunk * 4 + 2) * (KK * KK), r1);
  leafpair_n(in, leaf0 + 6, b, prod);
  lse_node(prod, W + (size_t)(offA + chunk * 4 + 3) * (KK * KK), r2);
  addv(r1, r2, prod);
  lse_node(prod, W + (size_t)(offB2 + chunk * 2 + 1) * (KK * KK), r1);
  addv(r0, r1, prod);
  lse_node(prod, W + (size_t)(offC + chunk) * (KK * KK), r0);

#pragma unroll
  for (int j = 0; j < KK; ++j)
    o[(size_t)chunk * (KK * BATCH) + j * BATCH + b] = r0[j];
}

// ---------------------------------------------------------------------------
// Kernel D: levels 10-11 (4 nodes -> 1) + final mixture logsumexp.
// grid (1, 8), block 64.
// ---------------------------------------------------------------------------
__global__ __launch_bounds__(64, 2) void kernD(const float* __restrict__ in,
                                               const float* __restrict__ W,
                                               const float* __restrict__ mixw,
                                               float* __restrict__ out) {
  const int lane = threadIdx.x;
  const int b = blockIdx.y * 64 + lane;

  float r0[KK], r1[KK], prod[KK];

  leafpair_n(in, 0, b, prod);
  lse_node(prod, W + (size_t)2044 * (KK * KK), r0);
  leafpair_n(in, 2, b, prod);
  lse_node(prod, W + (size_t)2045 * (KK * KK), r1);
  addv(r0, r1, prod);
  lse_node(prod, W + (size_t)2046 * (KK * KK), r0);

  // log_softmax of mix_logw (uniform across lanes -> scalar loads)
  float wv[KK];
#pragma unroll
  for (int i = 0; i < KK; ++i) wv[i] = mixw[i];
  const float wm = regmax_tree(wv);
  float ws = 0.0f;
#pragma unroll
  for (int i = 0; i < KK; ++i) ws += __expf(wv[i] - wm);
  const float lsew = __logf(ws) + wm;

  float t[KK];
#pragma unroll
  for (int j = 0; j < KK; ++j) t[j] = 2.0f * r0[j] + (wv[j] - lsew);
  const float m2 = regmax_tree(t);
  float ss = 0.0f;
#pragma unroll
  for (int j = 0; j < KK; ++j) ss += __expf(t[j] - m2);
  out[b] = __logf(ss) + m2;
}

// ---------------------------------------------------------------------------
extern "C" void kernel_launch(void* const* d_in, const int* in_sizes, int n_in,
                              void* d_out, int out_size, void* d_ws,
                              size_t ws_size, hipStream_t stream) {
  const float* x = (const float*)d_in[0];     // [512][2048][32]
  const float* W = (const float*)d_in[1];     // [2047][32][32]
  // d_in[2] = fold_idx: always (2f, 2f+1) pairs per level -> hardcoded
  const float* mixw = (const float*)d_in[3];  // [32]
  float* out = (float*)d_out;                 // [512]

  float* buf1 = (float*)d_ws;                               // [256][32][512]
  float* buf2 = buf1 + (size_t)256 * KK * BATCH;            // [32][32][512]
  float* buf3 = buf2 + (size_t)32 * KK * BATCH;             // [4][32][512]

  kernA<<<dim3(256, 8), 64, 0, stream>>>(x, W, buf1);
  kernMid<<<dim3(32, 8), 64, 0, stream>>>(buf1, W, buf2, 1792, 1920, 1984);
  kernMid<<<dim3(4, 8), 64, 0, stream>>>(buf2, W, buf3, 2016, 2032, 2040);
  kernD<<<dim3(1, 8), 64, 0, stream>>>(buf3, W, mixw, out);
}

// Round 3
// 351.126 us; speedup vs baseline: 1.6200x; 1.6200x over previous
//
#include <hip/hip_runtime.h>

#define KK 32
#define BATCH 512
#define DD 2048
#define ESTRIDE 36  // floats; 144 B row stride (16B-aligned for float4 LDS ops)

// ---------------------------------------------------------------------------
// j-split node: block = 256 threads = 4 waves; wave jg owns outputs
// j in [jg*8, jg*8+8) for 64 batch lanes. Per-thread inputs/outputs are the
// 8-element j-slices. e (exp of inputs) is exchanged via LDS; max via LDS.
// W access is wave-uniform (node index from blockIdx, jg via readfirstlane)
// -> scalar s_load broadcast, FMA operands come from SGPRs.
// ---------------------------------------------------------------------------
__device__ __forceinline__ void node8(const float p8[8],
                                      const float* __restrict__ Wn, int jg,
                                      int lane, float* __restrict__ e_lds,
                                      float* __restrict__ pm_lds,
                                      float o8[8]) {
  // partial max over my 8 inputs (3-deep tree)
  const float a0 = fmaxf(p8[0], p8[1]), a1 = fmaxf(p8[2], p8[3]);
  const float a2 = fmaxf(p8[4], p8[5]), a3 = fmaxf(p8[6], p8[7]);
  pm_lds[jg * 65 + lane] = fmaxf(fmaxf(a0, a1), fmaxf(a2, a3));
  __syncthreads();
  const float m = fmaxf(fmaxf(pm_lds[lane], pm_lds[65 + lane]),
                        fmaxf(pm_lds[130 + lane], pm_lds[195 + lane]));

  float4* ew = reinterpret_cast<float4*>(e_lds + lane * ESTRIDE + jg * 8);
  ew[0] = make_float4(__expf(p8[0] - m), __expf(p8[1] - m),
                      __expf(p8[2] - m), __expf(p8[3] - m));
  ew[1] = make_float4(__expf(p8[4] - m), __expf(p8[5] - m),
                      __expf(p8[6] - m), __expf(p8[7] - m));
  __syncthreads();

  // read all 32 e's for my batch lane (8 x float4, conflict-light)
  const float4* er = reinterpret_cast<const float4*>(e_lds + lane * ESTRIDE);
  float ea[KK];
#pragma unroll
  for (int q = 0; q < 8; ++q) {
    const float4 v = er[q];
    ea[4 * q + 0] = v.x;
    ea[4 * q + 1] = v.y;
    ea[4 * q + 2] = v.z;
    ea[4 * q + 3] = v.w;
  }

  float acc[8];
#pragma unroll
  for (int j = 0; j < 8; ++j) acc[j] = 0.0f;
  const float* __restrict__ Wj = Wn + jg * 8;  // SGPR-uniform column offset
#pragma unroll
  for (int i = 0; i < KK; ++i) {
#pragma unroll
    for (int j = 0; j < 8; ++j)
      acc[j] = fmaf(ea[i], Wj[i * KK + j], acc[j]);
  }
#pragma unroll
  for (int j = 0; j < 8; ++j) o8[j] = __logf(acc[j]) + m;
}

__device__ __forceinline__ void addv8(const float a[8], const float b[8],
                                      float o[8]) {
#pragma unroll
  for (int j = 0; j < 8; ++j) o[j] = a[j] + b[j];
}

// leaf pair from x (layout [B][D][K]); my 8-wide i-slice of both leaves
__device__ __forceinline__ void pairload_x(const float* __restrict__ xb,
                                           int leaf, int j0, float p[8]) {
  const float4* u = reinterpret_cast<const float4*>(xb + leaf * KK + j0);
  const float4* v = reinterpret_cast<const float4*>(xb + (leaf + 1) * KK + j0);
  const float4 u0 = u[0], u1 = u[1], v0 = v[0], v1 = v[1];
  p[0] = u0.x + v0.x; p[1] = u0.y + v0.y; p[2] = u0.z + v0.z; p[3] = u0.w + v0.w;
  p[4] = u1.x + v1.x; p[5] = u1.y + v1.y; p[6] = u1.z + v1.z; p[7] = u1.w + v1.w;
}

// leaf pair from node buffer (layout [node][K][BATCH]) -> coalesced
__device__ __forceinline__ void pairload_n(const float* __restrict__ in,
                                           int node, int j0, int b,
                                           float p[8]) {
  const float* p0 = in + (size_t)node * (KK * BATCH) + (size_t)j0 * BATCH + b;
  const float* p1 = p0 + (KK * BATCH);
#pragma unroll
  for (int k = 0; k < 8; ++k) p[k] = p0[k * BATCH] + p1[k * BATCH];
}

// ---------------------------------------------------------------------------
// kern1: levels 1-3 (2048 -> 256). grid (256, 8) x 256 threads.
// ---------------------------------------------------------------------------
__global__ __launch_bounds__(256) void kern1(const float* __restrict__ x,
                                             const float* __restrict__ W,
                                             float* __restrict__ o) {
  __shared__ float e_lds[64 * ESTRIDE];
  __shared__ float pm_lds[4 * 65];
  const int lane = threadIdx.x & 63;
  const int jg = __builtin_amdgcn_readfirstlane(threadIdx.x >> 6);
  const int j0 = jg * 8;
  const int b = blockIdx.y * 64 + lane;
  const int chunk = blockIdx.x;
  const float* xb = x + (size_t)b * (DD * KK) + (size_t)chunk * 8 * KK;

  float p[8], a0[8], a1[8], b0[8], b1[8], o8[8];

  pairload_x(xb, 0, j0, p);
  node8(p, W + (size_t)(chunk * 4 + 0) * (KK * KK), jg, lane, e_lds, pm_lds, a0);
  pairload_x(xb, 2, j0, p);
  node8(p, W + (size_t)(chunk * 4 + 1) * (KK * KK), jg, lane, e_lds, pm_lds, a1);
  addv8(a0, a1, p);
  node8(p, W + (size_t)(1024 + chunk * 2 + 0) * (KK * KK), jg, lane, e_lds, pm_lds, b0);
  pairload_x(xb, 4, j0, p);
  node8(p, W + (size_t)(chunk * 4 + 2) * (KK * KK), jg, lane, e_lds, pm_lds, a0);
  pairload_x(xb, 6, j0, p);
  node8(p, W + (size_t)(chunk * 4 + 3) * (KK * KK), jg, lane, e_lds, pm_lds, a1);
  addv8(a0, a1, p);
  node8(p, W + (size_t)(1024 + chunk * 2 + 1) * (KK * KK), jg, lane, e_lds, pm_lds, b1);
  addv8(b0, b1, p);
  node8(p, W + (size_t)(1536 + chunk) * (KK * KK), jg, lane, e_lds, pm_lds, o8);

#pragma unroll
  for (int j = 0; j < 8; ++j)
    o[(size_t)chunk * (KK * BATCH) + (size_t)(j0 + j) * BATCH + b] = o8[j];
}

// ---------------------------------------------------------------------------
// kernMid: 3 levels, 8 input nodes -> 1. grid (chunks, 8) x 256 threads.
// ---------------------------------------------------------------------------
__global__ __launch_bounds__(256) void kernMid(const float* __restrict__ in,
                                               const float* __restrict__ W,
                                               float* __restrict__ o, int offA,
                                               int offB2, int offC) {
  __shared__ float e_lds[64 * ESTRIDE];
  __shared__ float pm_lds[4 * 65];
  const int lane = threadIdx.x & 63;
  const int jg = __builtin_amdgcn_readfirstlane(threadIdx.x >> 6);
  const int j0 = jg * 8;
  const int b = blockIdx.y * 64 + lane;
  const int chunk = blockIdx.x;
  const int leaf0 = chunk * 8;

  float p[8], a0[8], a1[8], b0[8], b1[8], o8[8];

  pairload_n(in, leaf0 + 0, j0, b, p);
  node8(p, W + (size_t)(offA + chunk * 4 + 0) * (KK * KK), jg, lane, e_lds, pm_lds, a0);
  pairload_n(in, leaf0 + 2, j0, b, p);
  node8(p, W + (size_t)(offA + chunk * 4 + 1) * (KK * KK), jg, lane, e_lds, pm_lds, a1);
  addv8(a0, a1, p);
  node8(p, W + (size_t)(offB2 + chunk * 2 + 0) * (KK * KK), jg, lane, e_lds, pm_lds, b0);
  pairload_n(in, leaf0 + 4, j0, b, p);
  node8(p, W + (size_t)(offA + chunk * 4 + 2) * (KK * KK), jg, lane, e_lds, pm_lds, a0);
  pairload_n(in, leaf0 + 6, j0, b, p);
  node8(p, W + (size_t)(offA + chunk * 4 + 3) * (KK * KK), jg, lane, e_lds, pm_lds, a1);
  addv8(a0, a1, p);
  node8(p, W + (size_t)(offB2 + chunk * 2 + 1) * (KK * KK), jg, lane, e_lds, pm_lds, b1);
  addv8(b0, b1, p);
  node8(p, W + (size_t)(offC + chunk) * (KK * KK), jg, lane, e_lds, pm_lds, o8);

#pragma unroll
  for (int j = 0; j < 8; ++j)
    o[(size_t)chunk * (KK * BATCH) + (size_t)(j0 + j) * BATCH + b] = o8[j];
}

// ---------------------------------------------------------------------------
// kern4: levels 10-11 (4 -> 1) + mixture logsumexp. grid (1, 8) x 256.
// ---------------------------------------------------------------------------
__global__ __launch_bounds__(256) void kern4(const float* __restrict__ in,
                                             const float* __restrict__ W,
                                             const float* __restrict__ mixw,
                                             float* __restrict__ out) {
  __shared__ float e_lds[64 * ESTRIDE];
  __shared__ float pm_lds[4 * 65];
  const int lane = threadIdx.x & 63;
  const int jg = __builtin_amdgcn_readfirstlane(threadIdx.x >> 6);
  const int j0 = jg * 8;
  const int b = blockIdx.y * 64 + lane;

  float p[8], a0[8], a1[8], o8[8];

  pairload_n(in, 0, j0, b, p);
  node8(p, W + (size_t)2044 * (KK * KK), jg, lane, e_lds, pm_lds, a0);
  pairload_n(in, 2, j0, b, p);
  node8(p, W + (size_t)2045 * (KK * KK), jg, lane, e_lds, pm_lds, a1);
  addv8(a0, a1, p);
  node8(p, W + (size_t)2046 * (KK * KK), jg, lane, e_lds, pm_lds, o8);

  // log_softmax norm of mix_logw (wave-uniform scalar loads)
  float wv[KK];
#pragma unroll
  for (int i = 0; i < KK; ++i) wv[i] = mixw[i];
  float t[KK];
#pragma unroll
  for (int i = 0; i < KK; ++i) t[i] = wv[i];
#pragma unroll
  for (int s = KK / 2; s >= 1; s >>= 1)
#pragma unroll
    for (int i = 0; i < s; ++i) t[i] = fmaxf(t[i], t[i + s]);
  const float wm = t[0];
  float ws = 0.0f;
#pragma unroll
  for (int i = 0; i < KK; ++i) ws += __expf(wv[i] - wm);
  const float lsew = __logf(ws) + wm;

  // final logsumexp over j of 2*o + logw, j-split across 4 waves
  float t8[8];
#pragma unroll
  for (int j = 0; j < 8; ++j) t8[j] = 2.0f * o8[j] + (wv[j0 + j] - lsew);
  const float c0 = fmaxf(t8[0], t8[1]), c1 = fmaxf(t8[2], t8[3]);
  const float c2 = fmaxf(t8[4], t8[5]), c3 = fmaxf(t8[6], t8[7]);
  __syncthreads();  // pm_lds reads from last node8 done
  pm_lds[jg * 65 + lane] = fmaxf(fmaxf(c0, c1), fmaxf(c2, c3));
  __syncthreads();
  const float m2 = fmaxf(fmaxf(pm_lds[lane], pm_lds[65 + lane]),
                         fmaxf(pm_lds[130 + lane], pm_lds[195 + lane]));
  float ss = 0.0f;
#pragma unroll
  for (int j = 0; j < 8; ++j) ss += __expf(t8[j] - m2);
  __syncthreads();  // everyone has read pm_lds maxes
  pm_lds[jg * 65 + lane] = ss;
  __syncthreads();
  if (jg == 0) {
    const float s4 = (pm_lds[lane] + pm_lds[65 + lane]) +
                     (pm_lds[130 + lane] + pm_lds[195 + lane]);
    out[b] = __logf(s4) + m2;
  }
}

// ---------------------------------------------------------------------------
extern "C" void kernel_launch(void* const* d_in, const int* in_sizes, int n_in,
                              void* d_out, int out_size, void* d_ws,
                              size_t ws_size, hipStream_t stream) {
  const float* x = (const float*)d_in[0];     // [512][2048][32]
  const float* W = (const float*)d_in[1];     // [2047][32][32]
  // d_in[2] = fold_idx: always (2f, 2f+1) pairs per level -> hardcoded
  const float* mixw = (const float*)d_in[3];  // [32]
  float* out = (float*)d_out;                 // [512]

  float* buf1 = (float*)d_ws;                     // [256][32][512]
  float* buf2 = buf1 + (size_t)256 * KK * BATCH;  // [32][32][512]
  float* buf3 = buf2 + (size_t)32 * KK * BATCH;   // [4][32][512]

  kern1<<<dim3(256, 8), 256, 0, stream>>>(x, W, buf1);
  kernMid<<<dim3(32, 8), 256, 0, stream>>>(buf1, W, buf2, 1792, 1920, 1984);
  kernMid<<<dim3(4, 8), 256, 0, stream>>>(buf2, W, buf3, 2016, 2032, 2040);
  kern4<<<dim3(1, 8), 256, 0, stream>>>(buf3, W, mixw, out);
}